// Round 2
// baseline (800.838 us; speedup 1.0000x reference)
//
#include <hip/hip_runtime.h>

#define B_   1024
#define S_   128
#define H_   1024
#define V_   50000
#define EPSF 1e-10f

typedef float f32x4 __attribute__((ext_vector_type(4)));
typedef short s16x8 __attribute__((ext_vector_type(8)));  // 8 bf16 as raw bits

// ---------- async global->LDS, 16B per lane ----------
__device__ __forceinline__ void gload_lds16(const void* g, void* l) {
  __builtin_amdgcn_global_load_lds(
      (const __attribute__((address_space(1))) void*)g,
      (__attribute__((address_space(3))) void*)l, 16, 0, 0);
}

// split fp32 -> bf16 hi (truncate) + bf16 lo (residual, truncate)
// x ~= hi + lo with |err| <~ 2^-16 |x|
__device__ __forceinline__ void split8(f32x4 a, f32x4 b, s16x8& hi, s16x8& lo) {
  float x[8] = {a[0], a[1], a[2], a[3], b[0], b[1], b[2], b[3]};
#pragma unroll
  for (int j = 0; j < 8; ++j) {
    unsigned u = __float_as_uint(x[j]);
    hi[j] = (short)(u >> 16);
    float hf = __uint_as_float(u & 0xFFFF0000u);
    float l  = x[j] - hf;
    lo[j] = (short)(__float_as_uint(l) >> 16);
  }
}

// ================= GEMM: logits = hidden * W^T + b =================
// 128x128 tile, BK=32, 4 waves (2x2), per-wave 4x4 frags of 16x16x32 bf16,
// fp32 -> bf16 hi/lo split in-loop, 3 MFMA products (hh + hl + lh).
// fp32 tiles staged via global_load_lds (16B), XOR-swizzled (slot ^= row&7)
// with pre-swizzled global source; double-buffered, 1 barrier/iter.
constexpr int NBN = (V_ + 127) / 128;  // 391

__global__ __launch_bounds__(256, 2) void gemm_logits(
    const float* __restrict__ hid, const float* __restrict__ W,
    const float* __restrict__ bias, float* __restrict__ out) {
  __shared__ float ldsA[2][128 * 32];  // 16 KB each
  __shared__ float ldsB[2][128 * 32];

  // XCD-grouped decomposition: blocks sharing one W panel (same nb) get the
  // same bid%8 (same XCD) and sit within a 64-bid window (co-resident).
  int bid = blockIdx.x;
  int xcd = bid & 7;
  int t8  = bid >> 3;       // 0..391
  int mb  = t8 & 7;         // 0..7
  int nbg = t8 >> 3;        // 0..48
  int nb  = nbg * 8 + xcd;
  if (nb >= NBN) return;

  const int brow = mb * 128;
  const int bcol = nb * 128;
  const int tid  = threadIdx.x;
  const int lane = tid & 63;
  const int wid  = tid >> 6;
  const int wr   = wid >> 1;  // 0..1
  const int wc   = wid & 1;   // 0..1

  // staging source pointers (pre-swizzled chunk within each 32-float row)
  const float* gA[4];
  const float* gB[4];
#pragma unroll
  for (int i = 0; i < 4; ++i) {
    int row = i * 32 + (tid >> 3);
    int g   = (tid & 7) ^ (row & 7);
    gA[i] = hid + (size_t)(brow + row) * H_ + g * 4;
    int gv = bcol + row;
    if (gv > V_ - 1) gv = V_ - 1;  // clamp OOB vocab rows (dupe loads, masked store)
    gB[i] = W + (size_t)gv * H_ + g * 4;
  }

  auto stage = [&](int bufi, int k0) {
#pragma unroll
    for (int i = 0; i < 4; ++i)
      gload_lds16(gA[i] + k0, (char*)(&ldsA[bufi][0]) + i * 4096 + wid * 1024);
#pragma unroll
    for (int i = 0; i < 4; ++i)
      gload_lds16(gB[i] + k0, (char*)(&ldsB[bufi][0]) + i * 4096 + wid * 1024);
  };

  // per-frag swizzled LDS byte offsets (read slot = chunk ^ (row&7))
  const int kg  = lane >> 4;
  const int r15 = lane & 15;
  int offA0[4], offA1[4], offB0[4], offB1[4];
#pragma unroll
  for (int i = 0; i < 4; ++i) {
    int ra = wr * 64 + i * 16 + r15;
    int wa = ra & 7;
    offA0[i] = ra * 128 + ((((kg << 1) | 0) ^ wa) << 4);
    offA1[i] = ra * 128 + ((((kg << 1) | 1) ^ wa) << 4);
    int rb = wc * 64 + i * 16 + r15;
    int wb = rb & 7;
    offB0[i] = rb * 128 + ((((kg << 1) | 0) ^ wb) << 4);
    offB1[i] = rb * 128 + ((((kg << 1) | 1) ^ wb) << 4);
  }

  f32x4 acc[4][4];
#pragma unroll
  for (int i = 0; i < 4; ++i)
#pragma unroll
    for (int j = 0; j < 4; ++j) acc[i][j] = (f32x4){0.f, 0.f, 0.f, 0.f};

  stage(0, 0);
  __syncthreads();
  int buf = 0;
#pragma unroll 1
  for (int t = 0; t < 32; ++t) {
    if (t < 31) stage(buf ^ 1, (t + 1) * 32);
    const char* bA = (const char*)(&ldsA[buf][0]);
    const char* bB = (const char*)(&ldsB[buf][0]);
    s16x8 ah[4], al[4], bh[4], bl[4];
#pragma unroll
    for (int mi = 0; mi < 4; ++mi)
      split8(*(const f32x4*)(bA + offA0[mi]), *(const f32x4*)(bA + offA1[mi]),
             ah[mi], al[mi]);
#pragma unroll
    for (int ni = 0; ni < 4; ++ni)
      split8(*(const f32x4*)(bB + offB0[ni]), *(const f32x4*)(bB + offB1[ni]),
             bh[ni], bl[ni]);
#pragma unroll
    for (int mi = 0; mi < 4; ++mi)
#pragma unroll
      for (int ni = 0; ni < 4; ++ni) {
        acc[mi][ni] = __builtin_amdgcn_mfma_f32_16x16x32_bf16(ah[mi], bh[ni], acc[mi][ni], 0, 0, 0);
        acc[mi][ni] = __builtin_amdgcn_mfma_f32_16x16x32_bf16(ah[mi], bl[ni], acc[mi][ni], 0, 0, 0);
        acc[mi][ni] = __builtin_amdgcn_mfma_f32_16x16x32_bf16(al[mi], bh[ni], acc[mi][ni], 0, 0, 0);
      }
    __syncthreads();
    buf ^= 1;
  }

  // epilogue: + bias, store. C/D map: col=lane&15, row=(lane>>4)*4+j (m89).
  const int colbase = bcol + wc * 64 + r15;
  const int rowbase = brow + wr * 64 + ((lane >> 4) << 2);
#pragma unroll
  for (int ni = 0; ni < 4; ++ni) {
    int col = colbase + ni * 16;
    if (col < V_) {
      float bv = bias[col];
#pragma unroll
      for (int mi = 0; mi < 4; ++mi) {
        int row0 = rowbase + mi * 16;
#pragma unroll
        for (int j = 0; j < 4; ++j)
          out[(size_t)(row0 + j) * V_ + col] = acc[mi][ni][j] + bv;
      }
    }
  }
}

// ================= fused row finish =================
// Per row b (one block):
//   phase 1: Z = sum exp(mod_logit); copy gate; scatter dedup in LDS
//            (gathers pre-transform logits of scattered cols into LDS)
//   phase 2: stats: norm = (1-c)(1-p0) + c*sum(attn) + EPS - scat0
//   phase 3: in-place transform  out = log(exp(x)*st0 + EPS), col0/col4 special
//   phase 4: fixup scattered cols out = log(exp(x)*st0 + val/norm + EPS)
__global__ __launch_bounds__(256) void row_finish(
    float* __restrict__ out, const float* __restrict__ attn,
    const int* __restrict__ src, const int* __restrict__ algn) {
  __shared__ float sRed[4];
  __shared__ float sBro[4];  // 0:Z 1:cp 2:scat0
  __shared__ float sSt[4];   // 0:st0 1:st1 2:invn
  __shared__ float sVal[S_];
  __shared__ int   sTgt[S_];
  __shared__ int   rTgt[S_];
  __shared__ float rVal[S_];
  __shared__ float rLog[S_];

  const int b = blockIdx.x;
  const int tid = threadIdx.x;
  const int lane = tid & 63, wid = tid >> 6;
  float* row = out + (size_t)b * V_;

  // ---- phase 1a: Z over mod logits (bounded |x|<~6: no max-subtract) ----
  float z = 0.f;
  for (int c = tid; c < V_ / 4; c += 256) {
    f32x4 f = ((const f32x4*)row)[c];
    z += __expf(f[0]) + __expf(f[1]) + __expf(f[2]) + __expf(f[3]);
  }
#pragma unroll
  for (int off = 32; off; off >>= 1) z += __shfl_down(z, off);
  if (lane == 0) sRed[wid] = z;
  if (tid == 0) sBro[2] = 0.f;
  __syncthreads();
  if (tid == 0) {
    float Zr = sRed[0] + sRed[1] + sRed[2] + sRed[3];
    float l4 = row[4];
    sBro[0] = Zr - __expf(l4) + __expf(EPSF);  // replace COPY logit by 1e-10
    sBro[1] = 1.f / (1.f + __expf(-l4));       // sigmoid
  }
  __syncthreads();
  const float Z = sBro[0], cp = sBro[1];

  // ---- phase 1b: scatter prep + dedup ----
  if (tid < S_) {
    int sv = src[b * S_ + tid];
    sTgt[tid] = algn[sv];
    sVal[tid] = attn[b * S_ + tid] * cp;  // mul_attn
  }
  __syncthreads();
  float sumv = 0.f;
  if (tid < S_) {
    int tgt = sTgt[tid];
    bool first = true;
    float total = 0.f;
    for (int s2 = 0; s2 < S_; ++s2) {
      bool eq = (sTgt[s2] == tgt);
      if (eq && s2 < tid) first = false;
      if (eq) total += sVal[s2];
    }
    if (first && tgt != 0) {
      rTgt[tid] = tgt;
      rVal[tid] = total;
      rLog[tid] = row[tgt];  // pre-transform logit
    } else {
      rTgt[tid] = -1;
    }
    if (first && tgt == 0) sBro[2] = total;  // unique writer
    sumv = sVal[tid];
  }
#pragma unroll
  for (int off = 32; off; off >>= 1) sumv += __shfl_down(sumv, off);
  if (lane == 0) sRed[wid] = sumv;
  __syncthreads();

  // ---- phase 2: stats ----
  if (tid == 0) {
    float sumval = sRed[0] + sRed[1] + sRed[2] + sRed[3];
    float scat0  = sBro[2];
    float p0     = __expf(row[0]) / Z;
    float omc    = 1.f - cp;
    float norm   = omc + sumval + EPSF - p0 * omc - scat0;
    sSt[0] = omc / (Z * norm);                // st0
    sSt[1] = __logf(EPSF / norm + EPSF);      // col-0 value
    sSt[2] = 1.f / norm;                      // invn
  }
  __syncthreads();
  const float st0 = sSt[0], st1 = sSt[1], invn = sSt[2];

  // ---- phase 3: in-place transform (2nd pass hits L2/LLC) ----
  for (int c = tid; c < V_ / 4; c += 256) {
    f32x4 f = ((const f32x4*)row)[c];
    int vb  = c * 4;
    f32x4 r;
#pragma unroll
    for (int j = 0; j < 4; ++j) {
      float x = f[j];
      int v   = vb + j;
      if (v == 4) x = EPSF;
      float y = __logf(__expf(x) * st0 + EPSF);
      if (v == 0) y = st1;
      r[j] = y;
    }
    ((f32x4*)row)[c] = r;
  }
  __syncthreads();

  // ---- phase 4: scatter fixup ----
  if (tid < S_) {
    int t = rTgt[tid];
    if (t >= 0) {
      float x = (t == 4) ? EPSF : rLog[tid];
      row[t] = __logf(__expf(x) * st0 + invn * rVal[tid] + EPSF);
    }
  }
}

extern "C" void kernel_launch(void* const* d_in, const int* in_sizes, int n_in,
                              void* d_out, int out_size, void* d_ws,
                              size_t ws_size, hipStream_t stream) {
  const float* hid  = (const float*)d_in[0];
  const int*   src  = (const int*)d_in[1];
  const float* attn = (const float*)d_in[2];
  const float* W    = (const float*)d_in[3];
  const float* bias = (const float*)d_in[4];
  const int*   algn = (const int*)d_in[5];
  float* out = (float*)d_out;
  (void)in_sizes; (void)n_in; (void)out_size; (void)d_ws; (void)ws_size;

  gemm_logits<<<dim3(3136), dim3(256), 0, stream>>>(hid, W, bias, out);
  row_finish<<<dim3(B_), dim3(256), 0, stream>>>(out, attn, src, algn);
}

// Round 4
// 783.074 us; speedup vs baseline: 1.0227x; 1.0227x over previous
//
#include <hip/hip_runtime.h>

#define B_   1024
#define S_   128
#define H_   1024
#define V_   50000
#define EPSF 1e-10f

typedef float f32x4 __attribute__((ext_vector_type(4)));
typedef short s16x8 __attribute__((ext_vector_type(8)));  // 8 bf16 as raw bits
typedef short s16x4 __attribute__((ext_vector_type(4)));

// ws layout (pre-split path)
#define OFF_WHI 0ULL
#define OFF_WLO 102400000ULL
#define OFF_AHI 204800000ULL
#define OFF_ALO 206897152ULL
#define OFF_Z   208994304ULL
#define OFF_ST  208998400ULL
#define OFF_RT  209014784ULL
#define OFF_RV  209539072ULL
#define OFF_RL  210063360ULL
#define WS_NEED 210587648ULL

// ---------- async global->LDS, 16B per lane ----------
__device__ __forceinline__ void gload_lds16(const void* g, void* l) {
  __builtin_amdgcn_global_load_lds(
      (const __attribute__((address_space(1))) void*)g,
      (__attribute__((address_space(3))) void*)l, 16, 0, 0);
}

// split fp32 -> bf16 hi (truncate) + bf16 lo (residual, truncate)
__device__ __forceinline__ void split8(f32x4 a, f32x4 b, s16x8& hi, s16x8& lo) {
  float x[8] = {a[0], a[1], a[2], a[3], b[0], b[1], b[2], b[3]};
#pragma unroll
  for (int j = 0; j < 8; ++j) {
    unsigned u = __float_as_uint(x[j]);
    hi[j] = (short)(u >> 16);
    float hf = __uint_as_float(u & 0xFFFF0000u);
    float l  = x[j] - hf;
    lo[j] = (short)(__float_as_uint(l) >> 16);
  }
}

// ================= pre-split: fp32 -> bf16 hi/lo planes =================
__global__ __launch_bounds__(256) void split_planes(
    const float* __restrict__ in, short* __restrict__ hi,
    short* __restrict__ lo, int n4) {
  for (int g = blockIdx.x * 256 + threadIdx.x; g < n4; g += gridDim.x * 256) {
    f32x4 x = ((const f32x4*)in)[g];
    s16x4 h, l;
#pragma unroll
    for (int j = 0; j < 4; ++j) {
      unsigned u = __float_as_uint(x[j]);
      h[j] = (short)(u >> 16);
      float hf = __uint_as_float(u & 0xFFFF0000u);
      l[j] = (short)(__float_as_uint(x[j] - hf) >> 16);
    }
    ((s16x4*)hi)[g] = h;
    ((s16x4*)lo)[g] = l;
  }
}

__global__ void zeroZ(float* Z) { Z[blockIdx.x * 256 + threadIdx.x] = 0.f; }

// ================= GEMM (pre-split): logits = hidden*W^T + b, + row exp-sums =================
// 128x128 tile, BK=32, 4 waves (2x2), bf16 hi/lo tiles staged via global_load_lds.
// Inner loop: 16 ds_read_b128 (conflict-free layout) + 48 MFMA (3 passes over
// 16 independent accumulators). Epilogue: store logits, atomicAdd row exp-sums.
constexpr int NBN = (V_ + 127) / 128;  // 391

__global__ __launch_bounds__(256, 2) void gemm_ps(
    const short* __restrict__ Whi, const short* __restrict__ Wlo,
    const short* __restrict__ Ahi, const short* __restrict__ Alo,
    const float* __restrict__ bias, float* __restrict__ out,
    float* __restrict__ Z) {
  __shared__ short lds[2][4][128 * 32];  // [buf][Ahi,Alo,Bhi,Blo] 8KB each = 64KB

  int bid = blockIdx.x;
  int xcd = bid & 7;
  int t8  = bid >> 3;
  int mb  = t8 & 7;
  int nbg = t8 >> 3;
  int nb  = nbg * 8 + xcd;
  if (nb >= NBN) return;

  const int brow = mb * 128;
  const int bcol = nb * 128;
  const int tid  = threadIdx.x;
  const int lane = tid & 63;
  const int wid  = tid >> 6;
  const int wr   = wid >> 1;
  const int wc   = wid & 1;

  // staging: lane l of wave w -> row = w*16 + (l>>2), kchunk = (l&3)*8 shorts.
  const int rt0 = wid * 16 + (lane >> 2);
  const int kc8 = (lane & 3) * 8;
  const short* pAhi = Ahi + (size_t)(brow + rt0) * H_ + kc8;
  const short* pAlo = Alo + (size_t)(brow + rt0) * H_ + kc8;
  int gv0 = bcol + rt0;        if (gv0 > V_ - 1) gv0 = V_ - 1;
  int gv1 = bcol + 64 + rt0;   if (gv1 > V_ - 1) gv1 = V_ - 1;
  const short* pBhi0 = Whi + (size_t)gv0 * H_ + kc8;
  const short* pBhi1 = Whi + (size_t)gv1 * H_ + kc8;
  const short* pBlo0 = Wlo + (size_t)gv0 * H_ + kc8;
  const short* pBlo1 = Wlo + (size_t)gv1 * H_ + kc8;

  auto stage = [&](int bufi, int k0) {
    short* base = &lds[bufi][0][0];
    gload_lds16(pAhi + k0,          base +               wid * 512);
    gload_lds16(pAhi + 65536 + k0,  base + 2048 +        wid * 512);
    gload_lds16(pAlo + k0,          base + 4096 +        wid * 512);
    gload_lds16(pAlo + 65536 + k0,  base + 4096 + 2048 + wid * 512);
    gload_lds16(pBhi0 + k0,         base + 8192 +        wid * 512);
    gload_lds16(pBhi1 + k0,         base + 8192 + 2048 + wid * 512);
    gload_lds16(pBlo0 + k0,         base + 12288 +       wid * 512);
    gload_lds16(pBlo1 + k0,         base + 12288 + 2048 + wid * 512);
  };

  const int kg  = lane >> 4;
  const int r15 = lane & 15;
  const int arow = wr * 64 + r15;   // + mi*16
  const int brw  = wc * 64 + r15;   // + ni*16
  const int kofs = kg * 8;

  f32x4 acc[4][4];
#pragma unroll
  for (int i = 0; i < 4; ++i)
#pragma unroll
    for (int j = 0; j < 4; ++j) acc[i][j] = (f32x4){0.f, 0.f, 0.f, 0.f};

  stage(0, 0);
  __syncthreads();
  int buf = 0;
#pragma unroll 1
  for (int t = 0; t < 32; ++t) {
    if (t < 31) stage(buf ^ 1, (t + 1) * 32);
    const short* bp = &lds[buf][0][0];
    s16x8 ah[4], al[4], bh[4], bl[4];
#pragma unroll
    for (int mi = 0; mi < 4; ++mi) {
      ah[mi] = *(const s16x8*)(bp + (arow + mi * 16) * 32 + kofs);
      al[mi] = *(const s16x8*)(bp + 4096 + (arow + mi * 16) * 32 + kofs);
    }
#pragma unroll
    for (int ni = 0; ni < 4; ++ni) {
      bh[ni] = *(const s16x8*)(bp + 8192 + (brw + ni * 16) * 32 + kofs);
      bl[ni] = *(const s16x8*)(bp + 12288 + (brw + ni * 16) * 32 + kofs);
    }
    // 3 passes, 16 independent accumulators each -> no back-to-back C-dep
#pragma unroll
    for (int mi = 0; mi < 4; ++mi)
#pragma unroll
      for (int ni = 0; ni < 4; ++ni)
        acc[mi][ni] = __builtin_amdgcn_mfma_f32_16x16x32_bf16(ah[mi], bh[ni], acc[mi][ni], 0, 0, 0);
#pragma unroll
    for (int mi = 0; mi < 4; ++mi)
#pragma unroll
      for (int ni = 0; ni < 4; ++ni)
        acc[mi][ni] = __builtin_amdgcn_mfma_f32_16x16x32_bf16(ah[mi], bl[ni], acc[mi][ni], 0, 0, 0);
#pragma unroll
    for (int mi = 0; mi < 4; ++mi)
#pragma unroll
      for (int ni = 0; ni < 4; ++ni)
        acc[mi][ni] = __builtin_amdgcn_mfma_f32_16x16x32_bf16(al[mi], bh[ni], acc[mi][ni], 0, 0, 0);
    __syncthreads();
    buf ^= 1;
  }

  // epilogue: store logits (+bias) and per-row exp-sums into Z.
  const int colbase = bcol + wc * 64 + r15;
  const int rowbase = brow + wr * 64 + ((lane >> 4) << 2);
  float bv[4];
  bool  cv[4];
#pragma unroll
  for (int ni = 0; ni < 4; ++ni) {
    int col = colbase + ni * 16;
    cv[ni] = (col < V_);
    bv[ni] = bias[cv[ni] ? col : (V_ - 1)];
  }
#pragma unroll
  for (int ni = 0; ni < 4; ++ni) {
    if (cv[ni]) {
      int col = colbase + ni * 16;
#pragma unroll
      for (int mi = 0; mi < 4; ++mi) {
        int row0 = rowbase + mi * 16;
#pragma unroll
        for (int j = 0; j < 4; ++j)
          out[(size_t)(row0 + j) * V_ + col] = acc[mi][ni][j] + bv[ni];
      }
    }
  }
#pragma unroll
  for (int mi = 0; mi < 4; ++mi) {
#pragma unroll
    for (int j = 0; j < 4; ++j) {
      float s = 0.f;
#pragma unroll
      for (int ni = 0; ni < 4; ++ni)
        if (cv[ni]) s += __expf(acc[mi][ni][j] + bv[ni]);
      s += __shfl_xor(s, 1);
      s += __shfl_xor(s, 2);
      s += __shfl_xor(s, 4);
      s += __shfl_xor(s, 8);
      if (r15 == 0) atomicAdd(&Z[rowbase + mi * 16 + j], s);
    }
  }
}

// ================= stats per row =================
__global__ __launch_bounds__(128) void stats_k(
    const float* __restrict__ out, const float* __restrict__ attn,
    const int* __restrict__ src, const int* __restrict__ algn,
    const float* __restrict__ Z, f32x4* __restrict__ stats,
    int* __restrict__ rec_tgt, float* __restrict__ rec_val,
    float* __restrict__ rec_logit) {
  __shared__ float sVal[S_];
  __shared__ int   sTgt[S_];
  __shared__ float sRed[2];
  __shared__ float sScat0;

  const int b = blockIdx.x;
  const int tid = threadIdx.x;
  const int lane = tid & 63, wid = tid >> 6;
  const float* row = out + (size_t)b * V_;

  if (tid == 0) sScat0 = 0.f;
  const float l4 = row[4];
  const float cp = 1.f / (1.f + __expf(-l4));
  {
    int sv = src[b * S_ + tid];
    sTgt[tid] = algn[sv];
    sVal[tid] = attn[b * S_ + tid] * cp;
  }
  __syncthreads();
  int tgt = sTgt[tid];
  bool first = true;
  float total = 0.f;
  for (int s2 = 0; s2 < S_; ++s2) {
    bool eq = (sTgt[s2] == tgt);
    if (eq && s2 < tid) first = false;
    if (eq) total += sVal[s2];
  }
  int o = b * S_ + tid;
  if (first && tgt != 0) {
    rec_tgt[o]   = tgt;
    rec_val[o]   = total;
    rec_logit[o] = row[tgt];
  } else {
    rec_tgt[o] = -1;
  }
  if (first && tgt == 0) sScat0 = total;

  float sumv = sVal[tid];
#pragma unroll
  for (int off = 32; off; off >>= 1) sumv += __shfl_down(sumv, off);
  if (lane == 0) sRed[wid] = sumv;
  __syncthreads();
  if (tid == 0) {
    float sumval = sRed[0] + sRed[1];
    float Zmod   = Z[b] - __expf(l4) + __expf(EPSF);
    float p0     = __expf(row[0]) / Zmod;
    float omc    = 1.f - cp;
    float norm   = omc + sumval + EPSF - p0 * omc - sScat0;
    f32x4 st;
    st[0] = omc / (Zmod * norm);
    st[1] = __logf(EPSF / norm + EPSF);
    st[2] = 1.f / norm;
    st[3] = 0.f;
    stats[b] = st;
  }
}

// ================= final elementwise transform =================
__global__ __launch_bounds__(256) void transform_k(
    float* __restrict__ out, const f32x4* __restrict__ stats) {
  const int total = (B_ * (V_ / 4));
  const int gpr   = V_ / 4;
  for (int g = blockIdx.x * 256 + threadIdx.x; g < total;
       g += gridDim.x * 256) {
    int row = g / gpr;
    int cg  = g - row * gpr;
    f32x4 st = stats[row];
    f32x4 f  = ((const f32x4*)out)[g];
    int vb   = cg * 4;
    f32x4 r;
#pragma unroll
    for (int j = 0; j < 4; ++j) {
      float x = f[j];
      int v   = vb + j;
      if (v == 4) x = EPSF;
      float y = __logf(__expf(x) * st[0] + EPSF);
      if (v == 0) y = st[1];
      r[j] = y;
    }
    ((f32x4*)out)[g] = r;
  }
}

// ================= scatter fixup =================
__global__ __launch_bounds__(128) void fixup_k(
    float* __restrict__ out, const f32x4* __restrict__ stats,
    const int* __restrict__ rec_tgt, const float* __restrict__ rec_val,
    const float* __restrict__ rec_logit) {
  int b = blockIdx.x, s = threadIdx.x;
  int o = b * S_ + s;
  int t = rec_tgt[o];
  if (t < 0) return;
  f32x4 st = stats[b];
  float x  = (t == 4) ? EPSF : rec_logit[o];
  out[(size_t)b * V_ + t] = __logf(__expf(x) * st[0] + st[2] * rec_val[o] + EPSF);
}

// ======================================================================
// =============== FALLBACK path (ws too small): round-2 kernels ========
// ======================================================================
__global__ __launch_bounds__(256, 2) void gemm_fb(
    const float* __restrict__ hid, const float* __restrict__ W,
    const float* __restrict__ bias, float* __restrict__ out) {
  __shared__ float ldsA[2][128 * 32];
  __shared__ float ldsB[2][128 * 32];
  int bid = blockIdx.x;
  int xcd = bid & 7;
  int t8  = bid >> 3;
  int mb  = t8 & 7;
  int nbg = t8 >> 3;
  int nb  = nbg * 8 + xcd;
  if (nb >= NBN) return;
  const int brow = mb * 128;
  const int bcol = nb * 128;
  const int tid  = threadIdx.x;
  const int lane = tid & 63;
  const int wid  = tid >> 6;
  const int wr   = wid >> 1;
  const int wc   = wid & 1;
  const float* gA[4];
  const float* gB[4];
#pragma unroll
  for (int i = 0; i < 4; ++i) {
    int row = i * 32 + (tid >> 3);
    int g   = (tid & 7) ^ (row & 7);
    gA[i] = hid + (size_t)(brow + row) * H_ + g * 4;
    int gv = bcol + row;
    if (gv > V_ - 1) gv = V_ - 1;
    gB[i] = W + (size_t)gv * H_ + g * 4;
  }
  auto stage = [&](int bufi, int k0) {
#pragma unroll
    for (int i = 0; i < 4; ++i)
      gload_lds16(gA[i] + k0, (char*)(&ldsA[bufi][0]) + i * 4096 + wid * 1024);
#pragma unroll
    for (int i = 0; i < 4; ++i)
      gload_lds16(gB[i] + k0, (char*)(&ldsB[bufi][0]) + i * 4096 + wid * 1024);
  };
  const int kg  = lane >> 4;
  const int r15 = lane & 15;
  int offA0[4], offA1[4], offB0[4], offB1[4];
#pragma unroll
  for (int i = 0; i < 4; ++i) {
    int ra = wr * 64 + i * 16 + r15;
    int wa = ra & 7;
    offA0[i] = ra * 128 + ((((kg << 1) | 0) ^ wa) << 4);
    offA1[i] = ra * 128 + ((((kg << 1) | 1) ^ wa) << 4);
    int rb = wc * 64 + i * 16 + r15;
    int wb = rb & 7;
    offB0[i] = rb * 128 + ((((kg << 1) | 0) ^ wb) << 4);
    offB1[i] = rb * 128 + ((((kg << 1) | 1) ^ wb) << 4);
  }
  f32x4 acc[4][4];
#pragma unroll
  for (int i = 0; i < 4; ++i)
#pragma unroll
    for (int j = 0; j < 4; ++j) acc[i][j] = (f32x4){0.f, 0.f, 0.f, 0.f};
  stage(0, 0);
  __syncthreads();
  int buf = 0;
#pragma unroll 1
  for (int t = 0; t < 32; ++t) {
    if (t < 31) stage(buf ^ 1, (t + 1) * 32);
    const char* bA = (const char*)(&ldsA[buf][0]);
    const char* bB = (const char*)(&ldsB[buf][0]);
    s16x8 ah[4], al[4], bh[4], bl[4];
#pragma unroll
    for (int mi = 0; mi < 4; ++mi)
      split8(*(const f32x4*)(bA + offA0[mi]), *(const f32x4*)(bA + offA1[mi]),
             ah[mi], al[mi]);
#pragma unroll
    for (int ni = 0; ni < 4; ++ni)
      split8(*(const f32x4*)(bB + offB0[ni]), *(const f32x4*)(bB + offB1[ni]),
             bh[ni], bl[ni]);
#pragma unroll
    for (int mi = 0; mi < 4; ++mi)
#pragma unroll
      for (int ni = 0; ni < 4; ++ni) {
        acc[mi][ni] = __builtin_amdgcn_mfma_f32_16x16x32_bf16(ah[mi], bh[ni], acc[mi][ni], 0, 0, 0);
        acc[mi][ni] = __builtin_amdgcn_mfma_f32_16x16x32_bf16(ah[mi], bl[ni], acc[mi][ni], 0, 0, 0);
        acc[mi][ni] = __builtin_amdgcn_mfma_f32_16x16x32_bf16(al[mi], bh[ni], acc[mi][ni], 0, 0, 0);
      }
    __syncthreads();
    buf ^= 1;
  }
  const int colbase = bcol + wc * 64 + r15;
  const int rowbase = brow + wr * 64 + ((lane >> 4) << 2);
#pragma unroll
  for (int ni = 0; ni < 4; ++ni) {
    int col = colbase + ni * 16;
    if (col < V_) {
      float bv = bias[col];
#pragma unroll
      for (int mi = 0; mi < 4; ++mi) {
        int row0 = rowbase + mi * 16;
#pragma unroll
        for (int j = 0; j < 4; ++j)
          out[(size_t)(row0 + j) * V_ + col] = acc[mi][ni][j] + bv;
      }
    }
  }
}

__global__ __launch_bounds__(256) void row_finish(
    float* __restrict__ out, const float* __restrict__ attn,
    const int* __restrict__ src, const int* __restrict__ algn) {
  __shared__ float sRed[4];
  __shared__ float sBro[4];
  __shared__ float sSt[4];
  __shared__ float sVal[S_];
  __shared__ int   sTgt[S_];
  __shared__ int   rTgt[S_];
  __shared__ float rVal[S_];
  __shared__ float rLog[S_];
  const int b = blockIdx.x;
  const int tid = threadIdx.x;
  const int lane = tid & 63, wid = tid >> 6;
  float* row = out + (size_t)b * V_;
  float z = 0.f;
  for (int c = tid; c < V_ / 4; c += 256) {
    f32x4 f = ((const f32x4*)row)[c];
    z += __expf(f[0]) + __expf(f[1]) + __expf(f[2]) + __expf(f[3]);
  }
#pragma unroll
  for (int off = 32; off; off >>= 1) z += __shfl_down(z, off);
  if (lane == 0) sRed[wid] = z;
  if (tid == 0) sBro[2] = 0.f;
  __syncthreads();
  if (tid == 0) {
    float Zr = sRed[0] + sRed[1] + sRed[2] + sRed[3];
    float l4 = row[4];
    sBro[0] = Zr - __expf(l4) + __expf(EPSF);
    sBro[1] = 1.f / (1.f + __expf(-l4));
  }
  __syncthreads();
  const float Z = sBro[0], cp = sBro[1];
  if (tid < S_) {
    int sv = src[b * S_ + tid];
    sTgt[tid] = algn[sv];
    sVal[tid] = attn[b * S_ + tid] * cp;
  }
  __syncthreads();
  float sumv = 0.f;
  if (tid < S_) {
    int tgt = sTgt[tid];
    bool first = true;
    float total = 0.f;
    for (int s2 = 0; s2 < S_; ++s2) {
      bool eq = (sTgt[s2] == tgt);
      if (eq && s2 < tid) first = false;
      if (eq) total += sVal[s2];
    }
    if (first && tgt != 0) {
      rTgt[tid] = tgt;
      rVal[tid] = total;
      rLog[tid] = row[tgt];
    } else {
      rTgt[tid] = -1;
    }
    if (first && tgt == 0) sBro[2] = total;
    sumv = sVal[tid];
  }
#pragma unroll
  for (int off = 32; off; off >>= 1) sumv += __shfl_down(sumv, off);
  if (lane == 0) sRed[wid] = sumv;
  __syncthreads();
  if (tid == 0) {
    float sumval = sRed[0] + sRed[1] + sRed[2] + sRed[3];
    float scat0  = sBro[2];
    float p0     = __expf(row[0]) / Z;
    float omc    = 1.f - cp;
    float norm   = omc + sumval + EPSF - p0 * omc - scat0;
    sSt[0] = omc / (Z * norm);
    sSt[1] = __logf(EPSF / norm + EPSF);
    sSt[2] = 1.f / norm;
  }
  __syncthreads();
  const float st0 = sSt[0], st1 = sSt[1], invn = sSt[2];
  for (int c = tid; c < V_ / 4; c += 256) {
    f32x4 f = ((const f32x4*)row)[c];
    int vb  = c * 4;
    f32x4 r;
#pragma unroll
    for (int j = 0; j < 4; ++j) {
      float x = f[j];
      int v   = vb + j;
      if (v == 4) x = EPSF;
      float y = __logf(__expf(x) * st0 + EPSF);
      if (v == 0) y = st1;
      r[j] = y;
    }
    ((f32x4*)row)[c] = r;
  }
  __syncthreads();
  if (tid < S_) {
    int t = rTgt[tid];
    if (t >= 0) {
      float x = (t == 4) ? EPSF : rLog[tid];
      row[t] = __logf(__expf(x) * st0 + invn * rVal[tid] + EPSF);
    }
  }
}

extern "C" void kernel_launch(void* const* d_in, const int* in_sizes, int n_in,
                              void* d_out, int out_size, void* d_ws,
                              size_t ws_size, hipStream_t stream) {
  const float* hid  = (const float*)d_in[0];
  const int*   src  = (const int*)d_in[1];
  const float* attn = (const float*)d_in[2];
  const float* W    = (const float*)d_in[3];
  const float* bias = (const float*)d_in[4];
  const int*   algn = (const int*)d_in[5];
  float* out = (float*)d_out;
  (void)in_sizes; (void)n_in; (void)out_size;

  if (ws_size >= WS_NEED) {
    char* ws = (char*)d_ws;
    short* Whi = (short*)(ws + OFF_WHI);
    short* Wlo = (short*)(ws + OFF_WLO);
    short* Ahi = (short*)(ws + OFF_AHI);
    short* Alo = (short*)(ws + OFF_ALO);
    float* Z   = (float*)(ws + OFF_Z);
    f32x4* st  = (f32x4*)(ws + OFF_ST);
    int*   rt  = (int*)(ws + OFF_RT);
    float* rv  = (float*)(ws + OFF_RV);
    float* rl  = (float*)(ws + OFF_RL);

    split_planes<<<dim3(2048), dim3(256), 0, stream>>>(W, Whi, Wlo, V_ * H_ / 4);
    split_planes<<<dim3(256), dim3(256), 0, stream>>>(hid, Ahi, Alo, B_ * H_ / 4);
    zeroZ<<<dim3(4), dim3(256), 0, stream>>>(Z);
    gemm_ps<<<dim3(3136), dim3(256), 0, stream>>>(Whi, Wlo, Ahi, Alo, bias, out, Z);
    stats_k<<<dim3(B_), dim3(S_), 0, stream>>>(out, attn, src, algn, Z, st, rt, rv, rl);
    transform_k<<<dim3(2048), dim3(256), 0, stream>>>(out, st);
    fixup_k<<<dim3(B_), dim3(S_), 0, stream>>>(out, st, rt, rv, rl);
  } else {
    gemm_fb<<<dim3(3136), dim3(256), 0, stream>>>(hid, W, bias, out);
    row_finish<<<dim3(B_), dim3(256), 0, stream>>>(out, attn, src, algn);
  }
}